// Round 8
// baseline (395.063 us; speedup 1.0000x reference)
//
#include <hip/hip_runtime.h>
#include <math.h>

#define BZ 2
#define SQ 2048
#define DIN 1024
#define HH 16
#define NT 6144
#define MROWS 4096
#define KOUT 2048
#define KSPLIT 8

typedef unsigned short u16t;
typedef unsigned int u32t;
typedef __attribute__((ext_vector_type(8))) short bf16x8;
typedef __attribute__((ext_vector_type(4))) float f32x4;

__device__ __forceinline__ float cubef(float x) { return x * x * x; }

__device__ __forceinline__ u16t f2bf(float f) {          // fp32 -> bf16 RNE (unbiased)
    u32t b = __float_as_uint(f);
    b += 0x7FFFu + ((b >> 16) & 1u);
    return (u16t)(b >> 16);
}
__device__ __forceinline__ float bf2f(u16t u) { return __uint_as_float(((u32t)u) << 16); }
__device__ __forceinline__ u32t pk2(float a, float b) {
    return (u32t)f2bf(a) | ((u32t)f2bf(b) << 16);
}

#if __has_builtin(__builtin_amdgcn_exp2f)
#define EXP2(x) __builtin_amdgcn_exp2f(x)
#else
#define EXP2(x) exp2f(x)
#endif

// ---------------- K0: fused prep — bf16_x (2048 blk) + rope_table (512 blk) +
//                  transpose_w (1536 blk) in one launch ----------------
__global__ __launch_bounds__(256) void prep_all(const float* __restrict__ x,
                                                u16t* __restrict__ xb,
                                                float* __restrict__ tab,
                                                const float* __restrict__ W,
                                                u16t* __restrict__ Th) {
    __shared__ float tile[64][68];
    const int bx = blockIdx.x;
    const int t = threadIdx.x;

    if (bx < 2048) {
        const size_t idx = ((size_t)bx * 256 + t) * 8;
        float4 f0 = *(const float4*)&x[idx];
        float4 f1 = *(const float4*)&x[idx + 4];
        u32t h[4];
        h[0] = pk2(f0.x, f0.y); h[1] = pk2(f0.z, f0.w);
        h[2] = pk2(f1.x, f1.y); h[3] = pk2(f1.z, f1.w);
        *(uint4*)&xb[idx] = *(uint4*)&h[0];
    } else if (bx < 2560) {
        const int idx = (bx - 2048) * 256 + t;     // 0 .. 2048*64-1
        const int s = idx >> 6, d = idx & 63;
        float f = expf(-0.14391156831212788f * (float)d);
        float sn, cs;
        sincosf((float)s * f, &sn, &cs);
        ((float2*)tab)[idx] = make_float2(cs, sn);
    } else {
        const int idx = bx - 2560;                 // 0..1535
        const int n0 = (idx % 96) * 64;
        const int k0 = (idx / 96) * 64;
        {
            const int r = t >> 4, c = (t & 15) * 4;
            #pragma unroll
            for (int p = 0; p < 4; p++) {
                float4 v = *(const float4*)&W[(size_t)(k0 + r + p * 16) * NT + n0 + c];
                *(float4*)&tile[r + p * 16][c] = v;
            }
        }
        __syncthreads();
        const int nr = t >> 2;
        const int kc = (t & 3) * 16;
        u32t hi[8];
        #pragma unroll
        for (int j = 0; j < 8; j++)
            hi[j] = pk2(tile[kc + 2 * j][nr], tile[kc + 2 * j + 1][nr]);
        size_t ob = (size_t)(n0 + nr) * DIN + k0 + kc;
        *(uint4*)&Th[ob]     = *(uint4*)&hi[0];
        *(uint4*)&Th[ob + 8] = *(uint4*)&hi[4];
    }
}

// ---------------- K0b: proj_out [k][y] fp32 -> WTh [y][k] bf16 RNE ----------------
__global__ __launch_bounds__(256) void transpose_w2(const float* __restrict__ W,
                                                    u16t* __restrict__ Th) {
    __shared__ float tile[64][68];
    const int n0 = blockIdx.x * 64;
    const int k0 = blockIdx.y * 64;
    const int t = threadIdx.x;
    {
        const int r = t >> 4, c = (t & 15) * 4;
        #pragma unroll
        for (int p = 0; p < 4; p++) {
            float4 v = *(const float4*)&W[(size_t)(k0 + r + p * 16) * 128 + n0 + c];
            *(float4*)&tile[r + p * 16][c] = v;
        }
    }
    __syncthreads();
    const int nr = t >> 2;
    const int kc = (t & 3) * 16;
    u32t hi[8];
    #pragma unroll
    for (int j = 0; j < 8; j++)
        hi[j] = pk2(tile[kc + 2 * j][nr], tile[kc + 2 * j + 1][nr]);
    size_t ob = (size_t)(n0 + nr) * KOUT + k0 + kc;
    *(uint4*)&Th[ob]     = *(uint4*)&hi[0];
    *(uint4*)&Th[ob + 8] = *(uint4*)&hi[4];
}

#define QSC 0.12751744f   // (1/sqrt(128)) * log2(e)

// ---------------- K1: qkv GEMM — r6 single-barrier reg-staged loop (no setprio),
//                  128x128 tile, rect swizzle, fused rotary / V sigma-transpose ----------------
__global__ __launch_bounds__(256) void gemm_qkv11(const u16t* __restrict__ Ah,
                                                  const u16t* __restrict__ Bh,
                                                  const float* __restrict__ vb,
                                                  const float* __restrict__ ropetab,
                                                  u16t* __restrict__ QB,
                                                  u16t* __restrict__ KB,
                                                  u16t* __restrict__ VTh) {
    // staging: A bufs [0..8192), B bufs [8192..16384) halves; epilogue reuses
    // [0..17408) as a [128][136] bf16 tile. 34816 B -> 4 blocks/CU (LDS-bound).
    __shared__ __align__(16) u16t smem[17408];

    const int t = threadIdx.x;
    const int lane = t & 63, wid = t >> 6;
    const int quad = lane >> 4, l15 = lane & 15;
    const int wm = (wid & 1) * 64;
    const int wn = (wid >> 1) * 64;

    // XCD-group + 6x8 rect swizzle (bijective: 1536 = 8 XCD * 192)
    const int f = blockIdx.y * 48 + blockIdx.x;
    const int L = (f & 7) * 192 + (f >> 3);
    const int rect = L / 48, rrem = L - rect * 48;
    const int tileI = (rect & 7) * 6 + rrem % 6;        // 0..47 = h*3 + {q,k,v}
    const int rowIdx = (rect >> 3) * 8 + rrem / 6;      // 0..31
    const int h = tileI / 3, t3 = tileI - h * 3;
    const int colBase = tileI * 128;
    const int rowBase = rowIdx * 128;
    const int sm = t & 127;
    const int skh = t >> 7;

    f32x4 acc[4][4];
    #pragma unroll
    for (int i = 0; i < 4; i++)
        #pragma unroll
        for (int j = 0; j < 4; j++) acc[i][j] = (f32x4){0.f, 0.f, 0.f, 0.f};

    const u16t* aPtr = Ah + (size_t)(rowBase + sm) * DIN + skh * 16;
    const u16t* bPtr = Bh + (size_t)(colBase + sm) * DIN + skh * 16;
    const int swoff = skh * 2048 + sm * 8;    // halves within a buf

    // prefetch tile 0 into regs
    uint4 a0 = *(const uint4*)(aPtr);
    uint4 a1 = *(const uint4*)(aPtr + 8);
    uint4 b0 = *(const uint4*)(bPtr);
    uint4 b1 = *(const uint4*)(bPtr + 8);

    for (int it = 0; it < 32; it++) {
        const int buf = it & 1;
        const int ab = buf * 4096, bb_ = 8192 + buf * 4096;
        *(uint4*)(&smem[ab + swoff])         = a0;
        *(uint4*)(&smem[ab + swoff + 1024])  = a1;
        *(uint4*)(&smem[bb_ + swoff])        = b0;
        *(uint4*)(&smem[bb_ + swoff + 1024]) = b1;
        __syncthreads();          // publishes buf; no VM in flight -> cheap drain
        {   // issue next tile's loads — overlap compute below
            const int k0 = (it < 31) ? (it + 1) * 32 : it * 32;
            a0 = *(const uint4*)(aPtr + k0);
            a1 = *(const uint4*)(aPtr + k0 + 8);
            b0 = *(const uint4*)(bPtr + k0);
            b1 = *(const uint4*)(bPtr + k0 + 8);
        }
        bf16x8 ah[4], bh[4];
        #pragma unroll
        for (int mt = 0; mt < 4; mt++)
            ah[mt] = *(const bf16x8*)&smem[ab + quad * 1024 + (wm + mt * 16 + l15) * 8];
        #pragma unroll
        for (int nt = 0; nt < 4; nt++)
            bh[nt] = *(const bf16x8*)&smem[bb_ + quad * 1024 + (wn + nt * 16 + l15) * 8];
        #pragma unroll
        for (int mt = 0; mt < 4; mt++)
            #pragma unroll
            for (int nt = 0; nt < 4; nt++)
                acc[mt][nt] = __builtin_amdgcn_mfma_f32_16x16x32_bf16(ah[mt], bh[nt], acc[mt][nt], 0, 0, 0);
    }
    __syncthreads();     // retire all LDS reads before epilogue overwrites staging

    // ---------------- fused epilogue (r2/r6-proven) ----------------
    const int z = rowBase >> 11;
    const int s0local = rowBase & 2047;
    const size_t zh = (size_t)(z * 16 + h);
    u16t* tl = smem;                 // [128][136] bf16 tile

    if (t3 == 2) {
        #pragma unroll
        for (int nt = 0; nt < 4; nt++) {
            float bbv = vb[h * 128 + wn + nt * 16 + l15];
            #pragma unroll
            for (int mt = 0; mt < 4; mt++)
                #pragma unroll
                for (int r = 0; r < 4; r++)
                    tl[(wm + mt * 16 + quad * 4 + r) * 136 + wn + nt * 16 + l15] =
                        f2bf(acc[mt][nt][r] + bbv);
        }
    } else {
        #pragma unroll
        for (int nt = 0; nt < 4; nt++)
            #pragma unroll
            for (int mt = 0; mt < 4; mt++)
                #pragma unroll
                for (int r = 0; r < 4; r++)
                    tl[(wm + mt * 16 + quad * 4 + r) * 136 + wn + nt * 16 + l15] =
                        f2bf(acc[mt][nt][r]);
    }
    __syncthreads();

    if (t3 != 2) {
        // rotary on the tile; Q additionally scaled by QSC (exp2-ready scores)
        u16t* dstQK = (t3 ? KB : QB) + zh * 262144;
        const float sc = t3 ? 1.0f : QSC;
        const int rr = t >> 2;
        const int ch = (t & 3) << 4;      // x1 col chunk: 0,16,32,48
        #pragma unroll
        for (int half = 0; half < 2; half++) {
            const int row = rr + half * 64;
            const int s = s0local + row;
            const u16t* trow = &tl[row * 136];
            uint4 X1  = *(const uint4*)&trow[ch];
            uint4 X1b = *(const uint4*)&trow[ch + 8];
            uint4 X2  = *(const uint4*)&trow[ch + 64];
            uint4 X2b = *(const uint4*)&trow[ch + 72];
            u32t A_[8] = {X1.x, X1.y, X1.z, X1.w, X1b.x, X1b.y, X1b.z, X1b.w};
            u32t B_[8] = {X2.x, X2.y, X2.z, X2.w, X2b.x, X2b.y, X2b.z, X2b.w};
            u32t OA[8], OB[8];
            const float4* tb = (const float4*)&ropetab[(size_t)s * 128 + ch * 2];
            #pragma unroll
            for (int p = 0; p < 8; p++) {
                float4 tt = tb[p];                    // cs0, sn0, cs1, sn1
                float cs0 = tt.x * sc, sn0 = tt.y * sc;
                float cs1 = tt.z * sc, sn1 = tt.w * sc;
                float x1a = bf2f((u16t)(A_[p] & 0xFFFFu)), x1b = bf2f((u16t)(A_[p] >> 16));
                float x2a = bf2f((u16t)(B_[p] & 0xFFFFu)), x2b = bf2f((u16t)(B_[p] >> 16));
                OA[p] = pk2(x1a * cs0 - x2a * sn0, x1b * cs1 - x2b * sn1);
                OB[p] = pk2(x2a * cs0 + x1a * sn0, x2b * cs1 + x1b * sn1);
            }
            u16t* d0 = dstQK + (size_t)s * 128 + ch;
            *(uint4*)d0        = make_uint4(OA[0], OA[1], OA[2], OA[3]);
            *(uint4*)(d0 + 8)  = make_uint4(OA[4], OA[5], OA[6], OA[7]);
            *(uint4*)(d0 + 64) = make_uint4(OB[0], OB[1], OB[2], OB[3]);
            *(uint4*)(d0 + 72) = make_uint4(OB[4], OB[5], OB[6], OB[7]);
        }
    } else {
        // V: transpose to [key-tile][d][32 sigma-permuted key slots]
        u16t* dstV = VTh + zh * 262144 + (size_t)(s0local >> 5) * 4096;
        const int d = t & 127;
        const int g0 = t >> 7;
        #pragma unroll
        for (int gg = 0; gg < 2; gg++) {
            const int g = g0 + 2 * gg;
            const u16t* col = &tl[(g * 32) * 136 + d];
            u32t H[16];
            #pragma unroll
            for (int m = 0; m < 16; m++) {
                u32t lo = col[m * 136];
                u32t hi = col[(m + 16) * 136];
                H[m] = lo | (hi << 16);
            }
            u16t* dv = dstV + (size_t)g * 4096 + d * 32;
            *(uint4*)&dv[0]  = *(uint4*)&H[0];
            *(uint4*)&dv[8]  = *(uint4*)&H[4];
            *(uint4*)&dv[16] = *(uint4*)&H[8];
            *(uint4*)&dv[24] = *(uint4*)&H[12];
        }
    }
}

// ---------------- K3: attention v11 — K/V direct global->reg (L2-served), no loop
//                  barriers, independent waves, XCD-grouped (z,h) ----------------
__global__ __launch_bounds__(256, 2) void attn_kernel11(const u16t* __restrict__ QB,
                                                        const u16t* __restrict__ KB,
                                                        const u16t* __restrict__ VTh,
                                                        const int* __restrict__ mask,
                                                        u16t* __restrict__ O3b) {
    const int blk = blockIdx.x;
    // XCD swizzle: 512 blocks = 8 XCD x 4 (z,h) x 16 q-blocks -> all q-blocks of a
    // (z,h) share one XCD's L2 (K+V working set ~4 MB/XCD).
    const int xcd = blk & 7, loc = blk >> 3;
    const int zh = xcd * 4 + (loc >> 4);
    const int qt = loc & 15;
    const int z = zh >> 4, h = zh & 15;
    const int t  = threadIdx.x;
    const int lane = t & 63, wid = t >> 6;
    const int quad = lane >> 4, l15 = lane & 15;

    __shared__ __align__(16) u16t wlb[128 * 40];   // P bf16 (wave-private rows)

    const int q0 = qt * 128;
    const u16t* qb  = QB  + (size_t)zh * 262144;
    const u16t* kbg = KB  + (size_t)zh * 262144;
    const u16t* vhg = VTh + (size_t)zh * 262144;
    const int mb = z * SQ;

    bf16x8 qf[2][4];
    #pragma unroll
    for (int i = 0; i < 2; i++)
        #pragma unroll
        for (int kk = 0; kk < 4; kk++)
            qf[i][kk] = *(const bf16x8*)(qb + (size_t)(q0 + 16 * (2 * wid + i) + l15) * 128 + kk * 32 + quad * 8);

    int4 qm4[2];
    #pragma unroll
    for (int i = 0; i < 2; i++)
        qm4[i] = *(const int4*)&mask[mb + q0 + 16 * (2 * wid + i) + 4 * quad];
    const int qmr[2][4] = {{qm4[0].x, qm4[0].y, qm4[0].z, qm4[0].w},
                           {qm4[1].x, qm4[1].y, qm4[1].z, qm4[1].w}};
    int rowoff[2];
    #pragma unroll
    for (int i = 0; i < 2; i++) rowoff[i] = (16 * (2 * wid + i) + 4 * quad) * 40;

    f32x4 acc[2][8];
    #pragma unroll
    for (int i = 0; i < 2; i++)
        #pragma unroll
        for (int d = 0; d < 8; d++) acc[i][d] = (f32x4){0.f, 0.f, 0.f, 0.f};
    float dsum[2][4] = {{0.f, 0.f, 0.f, 0.f}, {0.f, 0.f, 0.f, 0.f}};

    for (int kt = 0; kt < 64; kt++) {
        // K fragments direct from global (64B-sectored: quads cover one 64B line)
        const u16t* kb0 = kbg + (size_t)kt * 4096;
        bf16x8 kf0[4], kf1[4];
        #pragma unroll
        for (int kk = 0; kk < 4; kk++) {
            kf0[kk] = *(const bf16x8*)(kb0 + l15 * 128 + kk * 32 + quad * 8);
            kf1[kk] = *(const bf16x8*)(kb0 + (16 + l15) * 128 + kk * 32 + quad * 8);
        }
        const int colm0 = mask[mb + kt * 32 + l15];
        const int colm1 = mask[mb + kt * 32 + 16 + l15];

        f32x4 s4[2][2];
        #pragma unroll
        for (int i = 0; i < 2; i++)
            #pragma unroll
            for (int n = 0; n < 2; n++) s4[i][n] = (f32x4){0.f, 0.f, 0.f, 0.f};
        __builtin_amdgcn_s_setprio(1);
        #pragma unroll
        for (int kk = 0; kk < 4; kk++) {
            s4[0][0] = __builtin_amdgcn_mfma_f32_16x16x32_bf16(qf[0][kk], kf0[kk], s4[0][0], 0, 0, 0);
            s4[0][1] = __builtin_amdgcn_mfma_f32_16x16x32_bf16(qf[0][kk], kf1[kk], s4[0][1], 0, 0, 0);
            s4[1][0] = __builtin_amdgcn_mfma_f32_16x16x32_bf16(qf[1][kk], kf0[kk], s4[1][0], 0, 0, 0);
            s4[1][1] = __builtin_amdgcn_mfma_f32_16x16x32_bf16(qf[1][kk], kf1[kk], s4[1][1], 0, 0, 0);
        }
        __builtin_amdgcn_s_setprio(0);
        {   // col mask + exp2 -> packed bf16 P (row mask applied at epilogue)
            #pragma unroll
            for (int i = 0; i < 2; i++)
                #pragma unroll
                for (int r = 0; r < 4; r++) {
                    float w0 = colm0 ? 0.f : EXP2(s4[i][0][r]);
                    float w1 = colm1 ? 0.f : EXP2(s4[i][1][r]);
                    dsum[i][r] += w0 + w1;
                    u32t pkw;
                    asm("v_cvt_pk_bf16_f32 %0, %1, %2" : "=v"(pkw) : "v"(w0), "v"(w1));
                    *(u32t*)&wlb[rowoff[i] + r * 40 + 2 * l15] = pkw;
                }
        }
        // P read-back: same-wave rows, lgkm ordering, no barrier
        bf16x8 pa[2];
        #pragma unroll
        for (int i = 0; i < 2; i++)
            pa[i] = *(const bf16x8*)&wlb[(16 * (2 * wid + i) + l15) * 40 + quad * 8];
        // V fragments direct from global (sigma-tiled layout, 64B-sectored)
        const u16t* vb0 = vhg + (size_t)kt * 4096;
        __builtin_amdgcn_s_setprio(1);
        #pragma unroll
        for (int dt = 0; dt < 8; dt++) {
            bf16x8 vh = *(const bf16x8*)(vb0 + (16 * dt + l15) * 32 + quad * 8);
            acc[0][dt] = __builtin_amdgcn_mfma_f32_16x16x32_bf16(pa[0], vh, acc[0][dt], 0, 0, 0);
            acc[1][dt] = __builtin_amdgcn_mfma_f32_16x16x32_bf16(pa[1], vh, acc[1][dt], 0, 0, 0);
        }
        __builtin_amdgcn_s_setprio(0);
    }

    #pragma unroll
    for (int i = 0; i < 2; i++)
        #pragma unroll
        for (int r = 0; r < 4; r++) {
            float v = dsum[i][r];
            v += __shfl_xor(v, 1);
            v += __shfl_xor(v, 2);
            v += __shfl_xor(v, 4);
            v += __shfl_xor(v, 8);
            dsum[i][r] = v;
        }

    #pragma unroll
    for (int i = 0; i < 2; i++)
        #pragma unroll
        for (int r = 0; r < 4; r++) {
            int row = 16 * (2 * wid + i) + 4 * quad + r;
            float inv = (qmr[i][r] || !(dsum[i][r] > 0.f)) ? 0.f : 1.f / dsum[i][r];
            u16t* dst = O3b + (size_t)(z * SQ + q0 + row) * KOUT + h * 128;
            #pragma unroll
            for (int dt = 0; dt < 8; dt++)
                dst[16 * dt + l15] = f2bf(cubef(acc[i][dt][r] * inv));
        }
}

// ---------------- K4: partial[s] = O3b[:, chunk] @ W[chunk, :] — 4-buf ring, KSPLIT=8 ----------------
__device__ __forceinline__ void load_lds16(const void* g, void* l) {
    __builtin_amdgcn_global_load_lds((const __attribute__((address_space(1))) void*)g,
                                     (__attribute__((address_space(3))) void*)l, 16, 0, 0);
}

#define GQ_WAITBAR(N) do {                                                 \
    asm volatile("s_waitcnt vmcnt(" #N ")" ::: "memory");                  \
    __builtin_amdgcn_s_barrier();                                          \
    __builtin_amdgcn_sched_barrier(0);                                     \
} while (0)

#define GQ_STAGE(TI) do {                                                  \
    const int _k0 = (TI) * 32;                                             \
    const int _bb = ((TI) & 3) * 8192;                                     \
    load_lds16(aPtr + _k0,     &smem[_bb + wbase]);                        \
    load_lds16(aPtr + _k0 + 8, &smem[_bb + wbase + 1024]);                 \
    load_lds16(bPtr + _k0,     &smem[_bb + 4096 + wbase]);                 \
    load_lds16(bPtr + _k0 + 8, &smem[_bb + 4096 + wbase + 1024]);          \
} while (0)

#define GQ_COMPUTE(TI) do {                                                \
    const int _bb = ((TI) & 3) * 8192;                                     \
    bf16x8 ah[4], bh[4];                                                   \
    _Pragma("unroll")                                                      \
    for (int mt = 0; mt < 4; mt++)                                         \
        ah[mt] = *(const bf16x8*)&smem[_bb + quad * 1024 + (wm + mt * 16 + l15) * 8]; \
    _Pragma("unroll")                                                      \
    for (int nt = 0; nt < 4; nt++)                                         \
        bh[nt] = *(const bf16x8*)&smem[_bb + 4096 + quad * 1024 + (wn + nt * 16 + l15) * 8]; \
    _Pragma("unroll")                                                      \
    for (int mt = 0; mt < 4; mt++)                                         \
        _Pragma("unroll")                                                  \
        for (int nt = 0; nt < 4; nt++)                                     \
            acc[mt][nt] = __builtin_amdgcn_mfma_f32_16x16x32_bf16(ah[mt], bh[nt], acc[mt][nt], 0, 0, 0); \
} while (0)

__global__ __launch_bounds__(256, 2) void final_gemm4(const u16t* __restrict__ Ab,
                                                      const u16t* __restrict__ Bh,
                                                      float* __restrict__ part) {
    __shared__ __align__(16) u16t smem[32768];

    const int t = threadIdx.x;
    const int lane = t & 63, wid = t >> 6;
    const int quad = lane >> 4, l15 = lane & 15;
    const int wm = (wid & 1) * 64;
    const int wn = (wid >> 1) * 64;
    const int rowBase = blockIdx.x * 128;
    const int kBase   = blockIdx.y * (KOUT / KSPLIT);   // 256
    const int sm = t & 127;
    const int skh = t >> 7;

    f32x4 acc[4][4];
    #pragma unroll
    for (int i = 0; i < 4; i++)
        #pragma unroll
        for (int j = 0; j < 4; j++) acc[i][j] = (f32x4){0.f, 0.f, 0.f, 0.f};

    const u16t* aPtr = Ab + (size_t)(rowBase + sm) * KOUT + kBase + skh * 16;
    const u16t* bPtr = Bh + (size_t)sm * KOUT + kBase + skh * 16;
    const int wbase = (wid >> 1) * 2048 + (wid & 1) * 512;

    // NIT = 8 tiles of K=32
    GQ_STAGE(0);
    GQ_STAGE(1);
    for (int i = 0; i < 6; i++) {
        GQ_STAGE(i + 2);
        GQ_WAITBAR(8);
        GQ_COMPUTE(i);
    }
    GQ_WAITBAR(4);
    GQ_COMPUTE(6);
    GQ_WAITBAR(0);
    GQ_COMPUTE(7);

    float* pbase = part + (size_t)blockIdx.y * ((size_t)MROWS * 128);
    #pragma unroll
    for (int mt = 0; mt < 4; mt++)
        #pragma unroll
        for (int nt = 0; nt < 4; nt++) {
            int col = wn + nt * 16 + l15;
            #pragma unroll
            for (int r = 0; r < 4; r++) {
                int row = rowBase + wm + mt * 16 + quad * 4 + r;
                pbase[(size_t)row * 128 + col] = acc[mt][nt][r];
            }
        }
}

// ---------------- K5: out = cube(sum partials + bias) ----------------
__global__ __launch_bounds__(256) void reduce_bias_cube(const float* __restrict__ part,
                                                        const float* __restrict__ bias,
                                                        float* __restrict__ out) {
    const int idx = (blockIdx.x * 256 + threadIdx.x) * 4;
    float4 s = {0.f, 0.f, 0.f, 0.f};
    #pragma unroll
    for (int p = 0; p < KSPLIT; p++) {
        float4 v = *(const float4*)&part[(size_t)p * ((size_t)MROWS * 128) + idx];
        s.x += v.x; s.y += v.y; s.z += v.z; s.w += v.w;
    }
    float4 b = *(const float4*)&bias[idx & 127];
    float4 r;
    r.x = cubef(s.x + b.x);
    r.y = cubef(s.y + b.y);
    r.z = cubef(s.z + b.z);
    r.w = cubef(s.w + b.w);
    *(float4*)&out[idx] = r;
}

extern "C" void kernel_launch(void* const* d_in, const int* in_sizes, int n_in,
                              void* d_out, int out_size, void* d_ws, size_t ws_size,
                              hipStream_t stream) {
    const float* x        = (const float*)d_in[0];
    const int*   mask     = (const int*)d_in[1];
    const float* proj_in  = (const float*)d_in[2];
    const float* v_bias   = (const float*)d_in[3];
    const float* proj_out = (const float*)d_in[4];
    const float* po_bias  = (const float*)d_in[5];
    float* out = (float*)d_out;

    u16t* QB  = (u16t*)d_ws;                      // 16 MB
    u16t* KB  = QB + (size_t)8388608;             // 16 MB
    u16t* VTh = KB + (size_t)8388608;             // 16 MB
    u16t* xb  = VTh + (size_t)8388608;            // 8 MB
    u16t* O3b = xb + (size_t)4194304;             // 16 MB
    u16t* pTh = O3b;                              // aliases O3b head (dead before attn)
    float* ropetab = (float*)(O3b + (size_t)6291456);   // aliases O3b tail
    u16t* WTh = QB;                               // 0.5 MB (dead after attn)
    float* partials = (float*)(WTh + (size_t)128 * KOUT);  // [8,4096,128] f32 16.8 MB

    prep_all<<<2048 + 512 + 1536, 256, 0, stream>>>(x, xb, ropetab, proj_in, pTh);
    gemm_qkv11<<<dim3(48, 32), 256, 0, stream>>>(xb, pTh, v_bias, ropetab, QB, KB, VTh);
    attn_kernel11<<<BZ * HH * (SQ / 128), 256, 0, stream>>>(QB, KB, VTh, mask, O3b);
    transpose_w2<<<dim3(2, KOUT / 64), 256, 0, stream>>>(proj_out, WTh);
    final_gemm4<<<dim3(MROWS / 128, KSPLIT), 256, 0, stream>>>(O3b, WTh, partials);
    reduce_bias_cube<<<(MROWS * 128) / (256 * 4), 256, 0, stream>>>(partials, po_bias, out);
}

// Round 9
// 314.242 us; speedup vs baseline: 1.2572x; 1.2572x over previous
//
#include <hip/hip_runtime.h>
#include <math.h>

#define BZ 2
#define SQ 2048
#define DIN 1024
#define HH 16
#define NT 6144
#define MROWS 4096
#define KOUT 2048
#define KSPLIT 8

typedef unsigned short u16t;
typedef unsigned int u32t;
typedef __attribute__((ext_vector_type(8))) short bf16x8;
typedef __attribute__((ext_vector_type(4))) float f32x4;

__device__ __forceinline__ float cubef(float x) { return x * x * x; }

__device__ __forceinline__ u16t f2bf(float f) {          // fp32 -> bf16 RNE (unbiased)
    u32t b = __float_as_uint(f);
    b += 0x7FFFu + ((b >> 16) & 1u);
    return (u16t)(b >> 16);
}
__device__ __forceinline__ float bf2f(u16t u) { return __uint_as_float(((u32t)u) << 16); }
__device__ __forceinline__ u32t pk2(float a, float b) {
    return (u32t)f2bf(a) | ((u32t)f2bf(b) << 16);
}

#if __has_builtin(__builtin_amdgcn_exp2f)
#define EXP2(x) __builtin_amdgcn_exp2f(x)
#else
#define EXP2(x) exp2f(x)
#endif

// direct global->LDS 16B (no VGPR round-trip). LDS dest wave-uniform base + lane*16.
__device__ __forceinline__ void load_lds16(const void* g, void* l) {
    __builtin_amdgcn_global_load_lds((const __attribute__((address_space(1))) void*)g,
                                     (__attribute__((address_space(3))) void*)l, 16, 0, 0);
}

// ---------------- K0: fused prep — bf16_x (2048 blk) + rope_table (512 blk) +
//                  transpose_w (1536 blk) in one launch ----------------
__global__ __launch_bounds__(256) void prep_all(const float* __restrict__ x,
                                                u16t* __restrict__ xb,
                                                float* __restrict__ tab,
                                                const float* __restrict__ W,
                                                u16t* __restrict__ Th) {
    __shared__ float tile[64][68];
    const int bx = blockIdx.x;
    const int t = threadIdx.x;

    if (bx < 2048) {
        const size_t idx = ((size_t)bx * 256 + t) * 8;
        float4 f0 = *(const float4*)&x[idx];
        float4 f1 = *(const float4*)&x[idx + 4];
        u32t h[4];
        h[0] = pk2(f0.x, f0.y); h[1] = pk2(f0.z, f0.w);
        h[2] = pk2(f1.x, f1.y); h[3] = pk2(f1.z, f1.w);
        *(uint4*)&xb[idx] = *(uint4*)&h[0];
    } else if (bx < 2560) {
        const int idx = (bx - 2048) * 256 + t;     // 0 .. 2048*64-1
        const int s = idx >> 6, d = idx & 63;
        float f = expf(-0.14391156831212788f * (float)d);
        float sn, cs;
        sincosf((float)s * f, &sn, &cs);
        ((float2*)tab)[idx] = make_float2(cs, sn);
    } else {
        const int idx = bx - 2560;                 // 0..1535
        const int n0 = (idx % 96) * 64;
        const int k0 = (idx / 96) * 64;
        {
            const int r = t >> 4, c = (t & 15) * 4;
            #pragma unroll
            for (int p = 0; p < 4; p++) {
                float4 v = *(const float4*)&W[(size_t)(k0 + r + p * 16) * NT + n0 + c];
                *(float4*)&tile[r + p * 16][c] = v;
            }
        }
        __syncthreads();
        const int nr = t >> 2;
        const int kc = (t & 3) * 16;
        u32t hi[8];
        #pragma unroll
        for (int j = 0; j < 8; j++)
            hi[j] = pk2(tile[kc + 2 * j][nr], tile[kc + 2 * j + 1][nr]);
        size_t ob = (size_t)(n0 + nr) * DIN + k0 + kc;
        *(uint4*)&Th[ob]     = *(uint4*)&hi[0];
        *(uint4*)&Th[ob + 8] = *(uint4*)&hi[4];
    }
}

// ---------------- K0b: proj_out [k][y] fp32 -> WTh [y][k] bf16 RNE ----------------
__global__ __launch_bounds__(256) void transpose_w2(const float* __restrict__ W,
                                                    u16t* __restrict__ Th) {
    __shared__ float tile[64][68];
    const int n0 = blockIdx.x * 64;
    const int k0 = blockIdx.y * 64;
    const int t = threadIdx.x;
    {
        const int r = t >> 4, c = (t & 15) * 4;
        #pragma unroll
        for (int p = 0; p < 4; p++) {
            float4 v = *(const float4*)&W[(size_t)(k0 + r + p * 16) * 128 + n0 + c];
            *(float4*)&tile[r + p * 16][c] = v;
        }
    }
    __syncthreads();
    const int nr = t >> 2;
    const int kc = (t & 3) * 16;
    u32t hi[8];
    #pragma unroll
    for (int j = 0; j < 8; j++)
        hi[j] = pk2(tile[kc + 2 * j][nr], tile[kc + 2 * j + 1][nr]);
    size_t ob = (size_t)(n0 + nr) * KOUT + k0 + kc;
    *(uint4*)&Th[ob]     = *(uint4*)&hi[0];
    *(uint4*)&Th[ob + 8] = *(uint4*)&hi[4];
}

#define QSC 0.12751744f   // (1/sqrt(128)) * log2(e)

// ---------------- K1: qkv GEMM — r6 single-barrier reg-staged loop (no setprio),
//                  128x128 tile, rect swizzle, fused rotary / V sigma-transpose ----------------
__global__ __launch_bounds__(256) void gemm_qkv11(const u16t* __restrict__ Ah,
                                                  const u16t* __restrict__ Bh,
                                                  const float* __restrict__ vb,
                                                  const float* __restrict__ ropetab,
                                                  u16t* __restrict__ QB,
                                                  u16t* __restrict__ KB,
                                                  u16t* __restrict__ VTh) {
    __shared__ __align__(16) u16t smem[17408];

    const int t = threadIdx.x;
    const int lane = t & 63, wid = t >> 6;
    const int quad = lane >> 4, l15 = lane & 15;
    const int wm = (wid & 1) * 64;
    const int wn = (wid >> 1) * 64;

    // XCD-group + 6x8 rect swizzle (bijective: 1536 = 8 XCD * 192)
    const int f = blockIdx.y * 48 + blockIdx.x;
    const int L = (f & 7) * 192 + (f >> 3);
    const int rect = L / 48, rrem = L - rect * 48;
    const int tileI = (rect & 7) * 6 + rrem % 6;        // 0..47 = h*3 + {q,k,v}
    const int rowIdx = (rect >> 3) * 8 + rrem / 6;      // 0..31
    const int h = tileI / 3, t3 = tileI - h * 3;
    const int colBase = tileI * 128;
    const int rowBase = rowIdx * 128;
    const int sm = t & 127;
    const int skh = t >> 7;

    f32x4 acc[4][4];
    #pragma unroll
    for (int i = 0; i < 4; i++)
        #pragma unroll
        for (int j = 0; j < 4; j++) acc[i][j] = (f32x4){0.f, 0.f, 0.f, 0.f};

    const u16t* aPtr = Ah + (size_t)(rowBase + sm) * DIN + skh * 16;
    const u16t* bPtr = Bh + (size_t)(colBase + sm) * DIN + skh * 16;
    const int swoff = skh * 2048 + sm * 8;

    uint4 a0 = *(const uint4*)(aPtr);
    uint4 a1 = *(const uint4*)(aPtr + 8);
    uint4 b0 = *(const uint4*)(bPtr);
    uint4 b1 = *(const uint4*)(bPtr + 8);

    for (int it = 0; it < 32; it++) {
        const int buf = it & 1;
        const int ab = buf * 4096, bb_ = 8192 + buf * 4096;
        *(uint4*)(&smem[ab + swoff])         = a0;
        *(uint4*)(&smem[ab + swoff + 1024])  = a1;
        *(uint4*)(&smem[bb_ + swoff])        = b0;
        *(uint4*)(&smem[bb_ + swoff + 1024]) = b1;
        __syncthreads();
        {
            const int k0 = (it < 31) ? (it + 1) * 32 : it * 32;
            a0 = *(const uint4*)(aPtr + k0);
            a1 = *(const uint4*)(aPtr + k0 + 8);
            b0 = *(const uint4*)(bPtr + k0);
            b1 = *(const uint4*)(bPtr + k0 + 8);
        }
        bf16x8 ah[4], bh[4];
        #pragma unroll
        for (int mt = 0; mt < 4; mt++)
            ah[mt] = *(const bf16x8*)&smem[ab + quad * 1024 + (wm + mt * 16 + l15) * 8];
        #pragma unroll
        for (int nt = 0; nt < 4; nt++)
            bh[nt] = *(const bf16x8*)&smem[bb_ + quad * 1024 + (wn + nt * 16 + l15) * 8];
        #pragma unroll
        for (int mt = 0; mt < 4; mt++)
            #pragma unroll
            for (int nt = 0; nt < 4; nt++)
                acc[mt][nt] = __builtin_amdgcn_mfma_f32_16x16x32_bf16(ah[mt], bh[nt], acc[mt][nt], 0, 0, 0);
    }
    __syncthreads();

    // ---------------- fused epilogue ----------------
    const int z = rowBase >> 11;
    const int s0local = rowBase & 2047;
    const size_t zh = (size_t)(z * 16 + h);
    u16t* tl = smem;                 // [128][136] bf16 tile

    if (t3 == 2) {
        #pragma unroll
        for (int nt = 0; nt < 4; nt++) {
            float bbv = vb[h * 128 + wn + nt * 16 + l15];
            #pragma unroll
            for (int mt = 0; mt < 4; mt++)
                #pragma unroll
                for (int r = 0; r < 4; r++)
                    tl[(wm + mt * 16 + quad * 4 + r) * 136 + wn + nt * 16 + l15] =
                        f2bf(acc[mt][nt][r] + bbv);
        }
    } else {
        #pragma unroll
        for (int nt = 0; nt < 4; nt++)
            #pragma unroll
            for (int mt = 0; mt < 4; mt++)
                #pragma unroll
                for (int r = 0; r < 4; r++)
                    tl[(wm + mt * 16 + quad * 4 + r) * 136 + wn + nt * 16 + l15] =
                        f2bf(acc[mt][nt][r]);
    }
    __syncthreads();

    if (t3 != 2) {
        u16t* dstQK = (t3 ? KB : QB) + zh * 262144;
        const float sc = t3 ? 1.0f : QSC;
        const int rr = t >> 2;
        const int ch = (t & 3) << 4;
        #pragma unroll
        for (int half = 0; half < 2; half++) {
            const int row = rr + half * 64;
            const int s = s0local + row;
            const u16t* trow = &tl[row * 136];
            uint4 X1  = *(const uint4*)&trow[ch];
            uint4 X1b = *(const uint4*)&trow[ch + 8];
            uint4 X2  = *(const uint4*)&trow[ch + 64];
            uint4 X2b = *(const uint4*)&trow[ch + 72];
            u32t A_[8] = {X1.x, X1.y, X1.z, X1.w, X1b.x, X1b.y, X1b.z, X1b.w};
            u32t B_[8] = {X2.x, X2.y, X2.z, X2.w, X2b.x, X2b.y, X2b.z, X2b.w};
            u32t OA[8], OB[8];
            const float4* tb = (const float4*)&ropetab[(size_t)s * 128 + ch * 2];
            #pragma unroll
            for (int p = 0; p < 8; p++) {
                float4 tt = tb[p];
                float cs0 = tt.x * sc, sn0 = tt.y * sc;
                float cs1 = tt.z * sc, sn1 = tt.w * sc;
                float x1a = bf2f((u16t)(A_[p] & 0xFFFFu)), x1b = bf2f((u16t)(A_[p] >> 16));
                float x2a = bf2f((u16t)(B_[p] & 0xFFFFu)), x2b = bf2f((u16t)(B_[p] >> 16));
                OA[p] = pk2(x1a * cs0 - x2a * sn0, x1b * cs1 - x2b * sn1);
                OB[p] = pk2(x2a * cs0 + x1a * sn0, x2b * cs1 + x1b * sn1);
            }
            u16t* d0 = dstQK + (size_t)s * 128 + ch;
            *(uint4*)d0        = make_uint4(OA[0], OA[1], OA[2], OA[3]);
            *(uint4*)(d0 + 8)  = make_uint4(OA[4], OA[5], OA[6], OA[7]);
            *(uint4*)(d0 + 64) = make_uint4(OB[0], OB[1], OB[2], OB[3]);
            *(uint4*)(d0 + 72) = make_uint4(OB[4], OB[5], OB[6], OB[7]);
        }
    } else {
        u16t* dstV = VTh + zh * 262144 + (size_t)(s0local >> 5) * 4096;
        const int d = t & 127;
        const int g0 = t >> 7;
        #pragma unroll
        for (int gg = 0; gg < 2; gg++) {
            const int g = g0 + 2 * gg;
            const u16t* col = &tl[(g * 32) * 136 + d];
            u32t H[16];
            #pragma unroll
            for (int m = 0; m < 16; m++) {
                u32t lo = col[m * 136];
                u32t hi = col[(m + 16) * 136];
                H[m] = lo | (hi << 16);
            }
            u16t* dv = dstV + (size_t)g * 4096 + d * 32;
            *(uint4*)&dv[0]  = *(uint4*)&H[0];
            *(uint4*)&dv[8]  = *(uint4*)&H[4];
            *(uint4*)&dv[16] = *(uint4*)&H[8];
            *(uint4*)&dv[24] = *(uint4*)&H[12];
        }
    }
}

// ---------------- K3: attention v12 — QBLK=256 (4 q-tiles/wave), 1 block/CU,
//                  LDS-staged K/V (r6 structure), K/V reads amortized 2x ----------------
__global__ __launch_bounds__(256, 1) void attn_kernel12(const u16t* __restrict__ QB,
                                                        const u16t* __restrict__ KB,
                                                        const u16t* __restrict__ VTh,
                                                        const int* __restrict__ mask,
                                                        u16t* __restrict__ O3b) {
    const int blk = blockIdx.x;
    // 256 blocks = 8 XCD x 4 zh x 8 q-blocks; all q-blocks of a zh share an XCD L2.
    const int xcd = blk & 7, loc = blk >> 3;
    const int zh = xcd * 4 + (loc >> 3);
    const int qt = loc & 7;
    const int z = zh >> 4, h = zh & 15;
    const int t  = threadIdx.x;
    const int lane = t & 63, wid = t >> 6;
    const int quad = lane >> 4, l15 = lane & 15;

    __shared__ __align__(16) u16t ks[2][32 * 136];    // K bf16 [key][d], dbuf
    __shared__ __align__(16) u16t vth[2][128 * 40];   // V^T bf16 [d][key-pos], dbuf
    __shared__ __align__(16) u16t wlb[256 * 40];      // P bf16 (wave-private rows)
    __shared__ int km[2][32];

    const int q0 = qt * 256;
    const u16t* qb  = QB  + (size_t)zh * 262144;
    const u16t* kb  = KB  + (size_t)zh * 262144;
    const u16t* vhg = VTh + (size_t)zh * 262144;
    const int mb = z * SQ;

    // wave owns q-16-tiles {4*wid .. 4*wid+3} (64 q-rows)
    bf16x8 qf[4][4];
    #pragma unroll
    for (int i = 0; i < 4; i++)
        #pragma unroll
        for (int kk = 0; kk < 4; kk++)
            qf[i][kk] = *(const bf16x8*)(qb + (size_t)(q0 + 16 * (4 * wid + i) + l15) * 128 + kk * 32 + quad * 8);

    int4 qm4[4];
    #pragma unroll
    for (int i = 0; i < 4; i++)
        qm4[i] = *(const int4*)&mask[mb + q0 + 16 * (4 * wid + i) + 4 * quad];
    const int qmr[4][4] = {{qm4[0].x, qm4[0].y, qm4[0].z, qm4[0].w},
                           {qm4[1].x, qm4[1].y, qm4[1].z, qm4[1].w},
                           {qm4[2].x, qm4[2].y, qm4[2].z, qm4[2].w},
                           {qm4[3].x, qm4[3].y, qm4[3].z, qm4[3].w}};
    int rowoff[4];
    #pragma unroll
    for (int i = 0; i < 4; i++) rowoff[i] = (16 * (4 * wid + i) + 4 * quad) * 40;

    const int srow = t >> 3, sco = (t & 7) * 16;     // K: [key srow][d sco..]
    const int sdd = t >> 1, sk0 = (t & 1) * 16;      // V: [d sdd][key sk0..]

    // prefetch tile 0
    uint4 ka, kb2, va, vb2;
    int kmv = 0;
    {
        ka  = *(const uint4*)(kb + t * 16);
        kb2 = *(const uint4*)(kb + t * 16 + 8);
        va  = *(const uint4*)(vhg + t * 16);
        vb2 = *(const uint4*)(vhg + t * 16 + 8);
        if (t < 32) kmv = mask[mb + t];
    }

    f32x4 acc[4][8];
    #pragma unroll
    for (int i = 0; i < 4; i++)
        #pragma unroll
        for (int d = 0; d < 8; d++) acc[i][d] = (f32x4){0.f, 0.f, 0.f, 0.f};
    float dsum[4][4];
    #pragma unroll
    for (int i = 0; i < 4; i++)
        #pragma unroll
        for (int r = 0; r < 4; r++) dsum[i][r] = 0.f;

    for (int it = 0; it < 64; it++) {
        const int buf = it & 1;
        *(uint4*)&ks[buf][srow * 136 + sco]     = ka;
        *(uint4*)&ks[buf][srow * 136 + sco + 8] = kb2;
        *(uint4*)&vth[buf][sdd * 40 + sk0]      = va;
        *(uint4*)&vth[buf][sdd * 40 + sk0 + 8]  = vb2;
        if (t < 32) km[buf][t] = kmv;

        __syncthreads();

        {   // prefetch next tile (full compute phase of latency cover)
            const int ktn = (it < 63) ? (it + 1) * 32 : it * 32;
            const u16t* src = kb + (size_t)ktn * 128 + t * 16;
            ka  = *(const uint4*)(src);
            kb2 = *(const uint4*)(src + 8);
            const u16t* srch = vhg + (size_t)(ktn >> 5) * 4096 + t * 16;
            va  = *(const uint4*)(srch);
            vb2 = *(const uint4*)(srch + 8);
            if (t < 32) kmv = mask[mb + ktn + t];
        }

        // QK^T: 4 q-tiles x 2 key-cols; kf reads amortized over 4 tiles
        f32x4 s4[4][2];
        #pragma unroll
        for (int i = 0; i < 4; i++)
            #pragma unroll
            for (int n = 0; n < 2; n++) s4[i][n] = (f32x4){0.f, 0.f, 0.f, 0.f};
        #pragma unroll
        for (int kk = 0; kk < 4; kk++) {
            bf16x8 kf0 = *(const bf16x8*)&ks[buf][l15 * 136 + kk * 32 + quad * 8];
            bf16x8 kf1 = *(const bf16x8*)&ks[buf][(16 + l15) * 136 + kk * 32 + quad * 8];
            #pragma unroll
            for (int i = 0; i < 4; i++) {
                s4[i][0] = __builtin_amdgcn_mfma_f32_16x16x32_bf16(qf[i][kk], kf0, s4[i][0], 0, 0, 0);
                s4[i][1] = __builtin_amdgcn_mfma_f32_16x16x32_bf16(qf[i][kk], kf1, s4[i][1], 0, 0, 0);
            }
        }
        {   // col mask + exp2 -> packed bf16 P (row mask applied at epilogue)
            int colm0 = km[buf][l15], colm1 = km[buf][16 + l15];
            #pragma unroll
            for (int i = 0; i < 4; i++)
                #pragma unroll
                for (int r = 0; r < 4; r++) {
                    float w0 = colm0 ? 0.f : EXP2(s4[i][0][r]);
                    float w1 = colm1 ? 0.f : EXP2(s4[i][1][r]);
                    dsum[i][r] += w0 + w1;
                    u32t pkw;
                    asm("v_cvt_pk_bf16_f32 %0, %1, %2" : "=v"(pkw) : "v"(w0), "v"(w1));
                    *(u32t*)&wlb[rowoff[i] + r * 40 + 2 * l15] = pkw;
                }
        }
        // P read-back: same-wave rows, lgkm ordering, no barrier
        bf16x8 pa[4];
        #pragma unroll
        for (int i = 0; i < 4; i++)
            pa[i] = *(const bf16x8*)&wlb[(16 * (4 * wid + i) + l15) * 40 + quad * 8];
        // P·V: vh reads amortized over 4 tiles
        #pragma unroll
        for (int dt = 0; dt < 8; dt++) {
            bf16x8 vh = *(const bf16x8*)&vth[buf][(16 * dt + l15) * 40 + quad * 8];
            #pragma unroll
            for (int i = 0; i < 4; i++)
                acc[i][dt] = __builtin_amdgcn_mfma_f32_16x16x32_bf16(pa[i], vh, acc[i][dt], 0, 0, 0);
        }
    }

    #pragma unroll
    for (int i = 0; i < 4; i++)
        #pragma unroll
        for (int r = 0; r < 4; r++) {
            float v = dsum[i][r];
            v += __shfl_xor(v, 1);
            v += __shfl_xor(v, 2);
            v += __shfl_xor(v, 4);
            v += __shfl_xor(v, 8);
            dsum[i][r] = v;
        }

    #pragma unroll
    for (int i = 0; i < 4; i++)
        #pragma unroll
        for (int r = 0; r < 4; r++) {
            int row = 16 * (4 * wid + i) + 4 * quad + r;
            float inv = (qmr[i][r] || !(dsum[i][r] > 0.f)) ? 0.f : 1.f / dsum[i][r];
            u16t* dst = O3b + (size_t)(z * SQ + q0 + row) * KOUT + h * 128;
            #pragma unroll
            for (int dt = 0; dt < 8; dt++)
                dst[16 * dt + l15] = f2bf(cubef(acc[i][dt][r] * inv));
        }
}

// ---------------- K4: partial[s] = O3b[:, chunk] @ W[chunk, :] — 4-buf ring, KSPLIT=8 ----------------
#define GQ_WAITBAR(N) do {                                                 \
    asm volatile("s_waitcnt vmcnt(" #N ")" ::: "memory");                  \
    __builtin_amdgcn_s_barrier();                                          \
    __builtin_amdgcn_sched_barrier(0);                                     \
} while (0)

#define GQ_STAGE(TI) do {                                                  \
    const int _k0 = (TI) * 32;                                             \
    const int _bb = ((TI) & 3) * 8192;                                     \
    load_lds16(aPtr + _k0,     &smem[_bb + wbase]);                        \
    load_lds16(aPtr + _k0 + 8, &smem[_bb + wbase + 1024]);                 \
    load_lds16(bPtr + _k0,     &smem[_bb + 4096 + wbase]);                 \
    load_lds16(bPtr + _k0 + 8, &smem[_bb + 4096 + wbase + 1024]);          \
} while (0)

#define GQ_COMPUTE(TI) do {                                                \
    const int _bb = ((TI) & 3) * 8192;                                     \
    bf16x8 ah[4], bh[4];                                                   \
    _Pragma("unroll")                                                      \
    for (int mt = 0; mt < 4; mt++)                                         \
        ah[mt] = *(const bf16x8*)&smem[_bb + quad * 1024 + (wm + mt * 16 + l15) * 8]; \
    _Pragma("unroll")                                                      \
    for (int nt = 0; nt < 4; nt++)                                         \
        bh[nt] = *(const bf16x8*)&smem[_bb + 4096 + quad * 1024 + (wn + nt * 16 + l15) * 8]; \
    _Pragma("unroll")                                                      \
    for (int mt = 0; mt < 4; mt++)                                         \
        _Pragma("unroll")                                                  \
        for (int nt = 0; nt < 4; nt++)                                     \
            acc[mt][nt] = __builtin_amdgcn_mfma_f32_16x16x32_bf16(ah[mt], bh[nt], acc[mt][nt], 0, 0, 0); \
} while (0)

__global__ __launch_bounds__(256, 2) void final_gemm4(const u16t* __restrict__ Ab,
                                                      const u16t* __restrict__ Bh,
                                                      float* __restrict__ part) {
    __shared__ __align__(16) u16t smem[32768];

    const int t = threadIdx.x;
    const int lane = t & 63, wid = t >> 6;
    const int quad = lane >> 4, l15 = lane & 15;
    const int wm = (wid & 1) * 64;
    const int wn = (wid >> 1) * 64;
    const int rowBase = blockIdx.x * 128;
    const int kBase   = blockIdx.y * (KOUT / KSPLIT);   // 256
    const int sm = t & 127;
    const int skh = t >> 7;

    f32x4 acc[4][4];
    #pragma unroll
    for (int i = 0; i < 4; i++)
        #pragma unroll
        for (int j = 0; j < 4; j++) acc[i][j] = (f32x4){0.f, 0.f, 0.f, 0.f};

    const u16t* aPtr = Ab + (size_t)(rowBase + sm) * KOUT + kBase + skh * 16;
    const u16t* bPtr = Bh + (size_t)sm * KOUT + kBase + skh * 16;
    const int wbase = (wid >> 1) * 2048 + (wid & 1) * 512;

    GQ_STAGE(0);
    GQ_STAGE(1);
    for (int i = 0; i < 6; i++) {
        GQ_STAGE(i + 2);
        GQ_WAITBAR(8);
        GQ_COMPUTE(i);
    }
    GQ_WAITBAR(4);
    GQ_COMPUTE(6);
    GQ_WAITBAR(0);
    GQ_COMPUTE(7);

    float* pbase = part + (size_t)blockIdx.y * ((size_t)MROWS * 128);
    #pragma unroll
    for (int mt = 0; mt < 4; mt++)
        #pragma unroll
        for (int nt = 0; nt < 4; nt++) {
            int col = wn + nt * 16 + l15;
            #pragma unroll
            for (int r = 0; r < 4; r++) {
                int row = rowBase + wm + mt * 16 + quad * 4 + r;
                pbase[(size_t)row * 128 + col] = acc[mt][nt][r];
            }
        }
}

// ---------------- K5: out = cube(sum partials + bias) ----------------
__global__ __launch_bounds__(256) void reduce_bias_cube(const float* __restrict__ part,
                                                        const float* __restrict__ bias,
                                                        float* __restrict__ out) {
    const int idx = (blockIdx.x * 256 + threadIdx.x) * 4;
    float4 s = {0.f, 0.f, 0.f, 0.f};
    #pragma unroll
    for (int p = 0; p < KSPLIT; p++) {
        float4 v = *(const float4*)&part[(size_t)p * ((size_t)MROWS * 128) + idx];
        s.x += v.x; s.y += v.y; s.z += v.z; s.w += v.w;
    }
    float4 b = *(const float4*)&bias[idx & 127];
    float4 r;
    r.x = cubef(s.x + b.x);
    r.y = cubef(s.y + b.y);
    r.z = cubef(s.z + b.z);
    r.w = cubef(s.w + b.w);
    *(float4*)&out[idx] = r;
}

extern "C" void kernel_launch(void* const* d_in, const int* in_sizes, int n_in,
                              void* d_out, int out_size, void* d_ws, size_t ws_size,
                              hipStream_t stream) {
    const float* x        = (const float*)d_in[0];
    const int*   mask     = (const int*)d_in[1];
    const float* proj_in  = (const float*)d_in[2];
    const float* v_bias   = (const float*)d_in[3];
    const float* proj_out = (const float*)d_in[4];
    const float* po_bias  = (const float*)d_in[5];
    float* out = (float*)d_out;

    u16t* QB  = (u16t*)d_ws;                      // 16 MB
    u16t* KB  = QB + (size_t)8388608;             // 16 MB
    u16t* VTh = KB + (size_t)8388608;             // 16 MB
    u16t* xb  = VTh + (size_t)8388608;            // 8 MB
    u16t* O3b = xb + (size_t)4194304;             // 16 MB
    u16t* pTh = O3b;                              // aliases O3b head (dead before attn)
    float* ropetab = (float*)(O3b + (size_t)6291456);   // aliases O3b tail
    u16t* WTh = QB;                               // 0.5 MB (dead after attn)
    float* partials = (float*)(WTh + (size_t)128 * KOUT);  // [8,4096,128] f32 16.8 MB

    prep_all<<<2048 + 512 + 1536, 256, 0, stream>>>(x, xb, ropetab, proj_in, pTh);
    gemm_qkv11<<<dim3(48, 32), 256, 0, stream>>>(xb, pTh, v_bias, ropetab, QB, KB, VTh);
    attn_kernel12<<<256, 256, 0, stream>>>(QB, KB, VTh, mask, O3b);
    transpose_w2<<<dim3(2, KOUT / 64), 256, 0, stream>>>(proj_out, WTh);
    final_gemm4<<<dim3(MROWS / 128, KSPLIT), 256, 0, stream>>>(O3b, WTh, partials);
    reduce_bias_cube<<<(MROWS * 128) / (256 * 4), 256, 0, stream>>>(partials, po_bias, out);
}

// Round 10
// 295.183 us; speedup vs baseline: 1.3384x; 1.0646x over previous
//
#include <hip/hip_runtime.h>
#include <math.h>

#define BZ 2
#define SQ 2048
#define DIN 1024
#define HH 16
#define NT 6144
#define MROWS 4096
#define KOUT 2048
#define KSPLIT 8

typedef unsigned short u16t;
typedef unsigned int u32t;
typedef __attribute__((ext_vector_type(8))) short bf16x8;
typedef __attribute__((ext_vector_type(4))) float f32x4;

__device__ __forceinline__ float cubef(float x) { return x * x * x; }

__device__ __forceinline__ u16t f2bf(float f) {          // fp32 -> bf16 RNE (unbiased)
    u32t b = __float_as_uint(f);
    b += 0x7FFFu + ((b >> 16) & 1u);
    return (u16t)(b >> 16);
}
__device__ __forceinline__ float bf2f(u16t u) { return __uint_as_float(((u32t)u) << 16); }
__device__ __forceinline__ u32t pk2(float a, float b) {
    return (u32t)f2bf(a) | ((u32t)f2bf(b) << 16);
}

#if __has_builtin(__builtin_amdgcn_exp2f)
#define EXP2(x) __builtin_amdgcn_exp2f(x)
#else
#define EXP2(x) exp2f(x)
#endif

// direct global->LDS 16B (no VGPR round-trip). LDS dest wave-uniform base + lane*16.
__device__ __forceinline__ void load_lds16(const void* g, void* l) {
    __builtin_amdgcn_global_load_lds((const __attribute__((address_space(1))) void*)g,
                                     (__attribute__((address_space(3))) void*)l, 16, 0, 0);
}

// ---------------- K0: fused prep — bf16_x (2048 blk) + rope_table (512 blk) +
//                  transpose_w (1536 blk) in one launch ----------------
__global__ __launch_bounds__(256) void prep_all(const float* __restrict__ x,
                                                u16t* __restrict__ xb,
                                                float* __restrict__ tab,
                                                const float* __restrict__ W,
                                                u16t* __restrict__ Th) {
    __shared__ float tile[64][68];
    const int bx = blockIdx.x;
    const int t = threadIdx.x;

    if (bx < 2048) {
        const size_t idx = ((size_t)bx * 256 + t) * 8;
        float4 f0 = *(const float4*)&x[idx];
        float4 f1 = *(const float4*)&x[idx + 4];
        u32t h[4];
        h[0] = pk2(f0.x, f0.y); h[1] = pk2(f0.z, f0.w);
        h[2] = pk2(f1.x, f1.y); h[3] = pk2(f1.z, f1.w);
        *(uint4*)&xb[idx] = *(uint4*)&h[0];
    } else if (bx < 2560) {
        const int idx = (bx - 2048) * 256 + t;     // 0 .. 2048*64-1
        const int s = idx >> 6, d = idx & 63;
        float f = expf(-0.14391156831212788f * (float)d);
        float sn, cs;
        sincosf((float)s * f, &sn, &cs);
        ((float2*)tab)[idx] = make_float2(cs, sn);
    } else {
        const int idx = bx - 2560;                 // 0..1535
        const int n0 = (idx % 96) * 64;
        const int k0 = (idx / 96) * 64;
        {
            const int r = t >> 4, c = (t & 15) * 4;
            #pragma unroll
            for (int p = 0; p < 4; p++) {
                float4 v = *(const float4*)&W[(size_t)(k0 + r + p * 16) * NT + n0 + c];
                *(float4*)&tile[r + p * 16][c] = v;
            }
        }
        __syncthreads();
        const int nr = t >> 2;
        const int kc = (t & 3) * 16;
        u32t hi[8];
        #pragma unroll
        for (int j = 0; j < 8; j++)
            hi[j] = pk2(tile[kc + 2 * j][nr], tile[kc + 2 * j + 1][nr]);
        size_t ob = (size_t)(n0 + nr) * DIN + k0 + kc;
        *(uint4*)&Th[ob]     = *(uint4*)&hi[0];
        *(uint4*)&Th[ob + 8] = *(uint4*)&hi[4];
    }
}

// ---------------- K0b: proj_out [k][y] fp32 -> WTh [y][k] bf16 RNE ----------------
__global__ __launch_bounds__(256) void transpose_w2(const float* __restrict__ W,
                                                    u16t* __restrict__ Th) {
    __shared__ float tile[64][68];
    const int n0 = blockIdx.x * 64;
    const int k0 = blockIdx.y * 64;
    const int t = threadIdx.x;
    {
        const int r = t >> 4, c = (t & 15) * 4;
        #pragma unroll
        for (int p = 0; p < 4; p++) {
            float4 v = *(const float4*)&W[(size_t)(k0 + r + p * 16) * 128 + n0 + c];
            *(float4*)&tile[r + p * 16][c] = v;
        }
    }
    __syncthreads();
    const int nr = t >> 2;
    const int kc = (t & 3) * 16;
    u32t hi[8];
    #pragma unroll
    for (int j = 0; j < 8; j++)
        hi[j] = pk2(tile[kc + 2 * j][nr], tile[kc + 2 * j + 1][nr]);
    size_t ob = (size_t)(n0 + nr) * KOUT + k0 + kc;
    *(uint4*)&Th[ob]     = *(uint4*)&hi[0];
    *(uint4*)&Th[ob + 8] = *(uint4*)&hi[4];
}

#define QSC 0.12751744f   // (1/sqrt(128)) * log2(e)

// ---------------- K1: qkv GEMM — r6 single-barrier reg-staged loop (no setprio),
//                  128x128 tile, rect swizzle, fused rotary / V sigma-transpose ----------------
__global__ __launch_bounds__(256) void gemm_qkv11(const u16t* __restrict__ Ah,
                                                  const u16t* __restrict__ Bh,
                                                  const float* __restrict__ vb,
                                                  const float* __restrict__ ropetab,
                                                  u16t* __restrict__ QB,
                                                  u16t* __restrict__ KB,
                                                  u16t* __restrict__ VTh) {
    __shared__ __align__(16) u16t smem[17408];

    const int t = threadIdx.x;
    const int lane = t & 63, wid = t >> 6;
    const int quad = lane >> 4, l15 = lane & 15;
    const int wm = (wid & 1) * 64;
    const int wn = (wid >> 1) * 64;

    // XCD-group + 6x8 rect swizzle (bijective: 1536 = 8 XCD * 192)
    const int f = blockIdx.y * 48 + blockIdx.x;
    const int L = (f & 7) * 192 + (f >> 3);
    const int rect = L / 48, rrem = L - rect * 48;
    const int tileI = (rect & 7) * 6 + rrem % 6;        // 0..47 = h*3 + {q,k,v}
    const int rowIdx = (rect >> 3) * 8 + rrem / 6;      // 0..31
    const int h = tileI / 3, t3 = tileI - h * 3;
    const int colBase = tileI * 128;
    const int rowBase = rowIdx * 128;
    const int sm = t & 127;
    const int skh = t >> 7;

    f32x4 acc[4][4];
    #pragma unroll
    for (int i = 0; i < 4; i++)
        #pragma unroll
        for (int j = 0; j < 4; j++) acc[i][j] = (f32x4){0.f, 0.f, 0.f, 0.f};

    const u16t* aPtr = Ah + (size_t)(rowBase + sm) * DIN + skh * 16;
    const u16t* bPtr = Bh + (size_t)(colBase + sm) * DIN + skh * 16;
    const int swoff = skh * 2048 + sm * 8;

    uint4 a0 = *(const uint4*)(aPtr);
    uint4 a1 = *(const uint4*)(aPtr + 8);
    uint4 b0 = *(const uint4*)(bPtr);
    uint4 b1 = *(const uint4*)(bPtr + 8);

    for (int it = 0; it < 32; it++) {
        const int buf = it & 1;
        const int ab = buf * 4096, bb_ = 8192 + buf * 4096;
        *(uint4*)(&smem[ab + swoff])         = a0;
        *(uint4*)(&smem[ab + swoff + 1024])  = a1;
        *(uint4*)(&smem[bb_ + swoff])        = b0;
        *(uint4*)(&smem[bb_ + swoff + 1024]) = b1;
        __syncthreads();
        {
            const int k0 = (it < 31) ? (it + 1) * 32 : it * 32;
            a0 = *(const uint4*)(aPtr + k0);
            a1 = *(const uint4*)(aPtr + k0 + 8);
            b0 = *(const uint4*)(bPtr + k0);
            b1 = *(const uint4*)(bPtr + k0 + 8);
        }
        bf16x8 ah[4], bh[4];
        #pragma unroll
        for (int mt = 0; mt < 4; mt++)
            ah[mt] = *(const bf16x8*)&smem[ab + quad * 1024 + (wm + mt * 16 + l15) * 8];
        #pragma unroll
        for (int nt = 0; nt < 4; nt++)
            bh[nt] = *(const bf16x8*)&smem[bb_ + quad * 1024 + (wn + nt * 16 + l15) * 8];
        #pragma unroll
        for (int mt = 0; mt < 4; mt++)
            #pragma unroll
            for (int nt = 0; nt < 4; nt++)
                acc[mt][nt] = __builtin_amdgcn_mfma_f32_16x16x32_bf16(ah[mt], bh[nt], acc[mt][nt], 0, 0, 0);
    }
    __syncthreads();

    // ---------------- fused epilogue ----------------
    const int z = rowBase >> 11;
    const int s0local = rowBase & 2047;
    const size_t zh = (size_t)(z * 16 + h);
    u16t* tl = smem;                 // [128][136] bf16 tile

    if (t3 == 2) {
        #pragma unroll
        for (int nt = 0; nt < 4; nt++) {
            float bbv = vb[h * 128 + wn + nt * 16 + l15];
            #pragma unroll
            for (int mt = 0; mt < 4; mt++)
                #pragma unroll
                for (int r = 0; r < 4; r++)
                    tl[(wm + mt * 16 + quad * 4 + r) * 136 + wn + nt * 16 + l15] =
                        f2bf(acc[mt][nt][r] + bbv);
        }
    } else {
        #pragma unroll
        for (int nt = 0; nt < 4; nt++)
            #pragma unroll
            for (int mt = 0; mt < 4; mt++)
                #pragma unroll
                for (int r = 0; r < 4; r++)
                    tl[(wm + mt * 16 + quad * 4 + r) * 136 + wn + nt * 16 + l15] =
                        f2bf(acc[mt][nt][r]);
    }
    __syncthreads();

    if (t3 != 2) {
        u16t* dstQK = (t3 ? KB : QB) + zh * 262144;
        const float sc = t3 ? 1.0f : QSC;
        const int rr = t >> 2;
        const int ch = (t & 3) << 4;
        #pragma unroll
        for (int half = 0; half < 2; half++) {
            const int row = rr + half * 64;
            const int s = s0local + row;
            const u16t* trow = &tl[row * 136];
            uint4 X1  = *(const uint4*)&trow[ch];
            uint4 X1b = *(const uint4*)&trow[ch + 8];
            uint4 X2  = *(const uint4*)&trow[ch + 64];
            uint4 X2b = *(const uint4*)&trow[ch + 72];
            u32t A_[8] = {X1.x, X1.y, X1.z, X1.w, X1b.x, X1b.y, X1b.z, X1b.w};
            u32t B_[8] = {X2.x, X2.y, X2.z, X2.w, X2b.x, X2b.y, X2b.z, X2b.w};
            u32t OA[8], OB[8];
            const float4* tb = (const float4*)&ropetab[(size_t)s * 128 + ch * 2];
            #pragma unroll
            for (int p = 0; p < 8; p++) {
                float4 tt = tb[p];
                float cs0 = tt.x * sc, sn0 = tt.y * sc;
                float cs1 = tt.z * sc, sn1 = tt.w * sc;
                float x1a = bf2f((u16t)(A_[p] & 0xFFFFu)), x1b = bf2f((u16t)(A_[p] >> 16));
                float x2a = bf2f((u16t)(B_[p] & 0xFFFFu)), x2b = bf2f((u16t)(B_[p] >> 16));
                OA[p] = pk2(x1a * cs0 - x2a * sn0, x1b * cs1 - x2b * sn1);
                OB[p] = pk2(x2a * cs0 + x1a * sn0, x2b * cs1 + x1b * sn1);
            }
            u16t* d0 = dstQK + (size_t)s * 128 + ch;
            *(uint4*)d0        = make_uint4(OA[0], OA[1], OA[2], OA[3]);
            *(uint4*)(d0 + 8)  = make_uint4(OA[4], OA[5], OA[6], OA[7]);
            *(uint4*)(d0 + 64) = make_uint4(OB[0], OB[1], OB[2], OB[3]);
            *(uint4*)(d0 + 72) = make_uint4(OB[4], OB[5], OB[6], OB[7]);
        }
    } else {
        u16t* dstV = VTh + zh * 262144 + (size_t)(s0local >> 5) * 4096;
        const int d = t & 127;
        const int g0 = t >> 7;
        #pragma unroll
        for (int gg = 0; gg < 2; gg++) {
            const int g = g0 + 2 * gg;
            const u16t* col = &tl[(g * 32) * 136 + d];
            u32t H[16];
            #pragma unroll
            for (int m = 0; m < 16; m++) {
                u32t lo = col[m * 136];
                u32t hi = col[(m + 16) * 136];
                H[m] = lo | (hi << 16);
            }
            u16t* dv = dstV + (size_t)g * 4096 + d * 32;
            *(uint4*)&dv[0]  = *(uint4*)&H[0];
            *(uint4*)&dv[8]  = *(uint4*)&H[4];
            *(uint4*)&dv[16] = *(uint4*)&H[8];
            *(uint4*)&dv[24] = *(uint4*)&H[12];
        }
    }
}

// ---------------- K3: attention v13 — r6 attn9 structure (QBLK=128, 2 blk/CU) +
//                  XCD-grouped (z,h) + direct global mask loads ----------------
__global__ __launch_bounds__(256, 2) void attn_kernel13(const u16t* __restrict__ QB,
                                                        const u16t* __restrict__ KB,
                                                        const u16t* __restrict__ VTh,
                                                        const int* __restrict__ mask,
                                                        u16t* __restrict__ O3b) {
    const int blk = blockIdx.x;
    // 512 blocks = 8 XCD x 4 zh x 16 qt: all q-blocks of a zh share one XCD's L2
    // (K+V working set ~4 MB/XCD -> L2-fit). Bijective.
    const int xcd = blk & 7, loc = blk >> 3;
    const int zhl = xcd * 4 + (loc >> 4);
    const int qt = loc & 15;
    const int z = zhl >> 4, h = zhl & 15;
    const int t  = threadIdx.x;
    const int lane = t & 63, wid = t >> 6;
    const int quad = lane >> 4, l15 = lane & 15;

    __shared__ __align__(16) u16t ks[2][32 * 136];
    __shared__ __align__(16) u16t vth[2][128 * 40];
    __shared__ __align__(16) u16t wlb[128 * 40];

    const int q0 = qt * 128;
    const u16t* qb  = QB  + (size_t)zhl * 262144;
    const u16t* kb  = KB  + (size_t)zhl * 262144;
    const u16t* vhg = VTh + (size_t)zhl * 262144;
    const int mb = z * SQ;

    bf16x8 qf[2][4];
    #pragma unroll
    for (int i = 0; i < 2; i++)
        #pragma unroll
        for (int kk = 0; kk < 4; kk++)
            qf[i][kk] = *(const bf16x8*)(qb + (size_t)(q0 + 16 * (2 * wid + i) + l15) * 128 + kk * 32 + quad * 8);

    int4 qm4[2];
    #pragma unroll
    for (int i = 0; i < 2; i++)
        qm4[i] = *(const int4*)&mask[mb + q0 + 16 * (2 * wid + i) + 4 * quad];
    const int qmr[2][4] = {{qm4[0].x, qm4[0].y, qm4[0].z, qm4[0].w},
                           {qm4[1].x, qm4[1].y, qm4[1].z, qm4[1].w}};
    int rowoff[2];
    #pragma unroll
    for (int i = 0; i < 2; i++) rowoff[i] = (16 * (2 * wid + i) + 4 * quad) * 40;

    const int srow = t >> 3, sco = (t & 7) * 16;
    const int sdd = t >> 1, sk0 = (t & 1) * 16;

    uint4 ka, kb2, va, vb2;
    {
        ka  = *(const uint4*)(kb + t * 16);
        kb2 = *(const uint4*)(kb + t * 16 + 8);
        va  = *(const uint4*)(vhg + t * 16);
        vb2 = *(const uint4*)(vhg + t * 16 + 8);
    }

    f32x4 acc[2][8];
    #pragma unroll
    for (int i = 0; i < 2; i++)
        #pragma unroll
        for (int d = 0; d < 8; d++) acc[i][d] = (f32x4){0.f, 0.f, 0.f, 0.f};
    float dsum[2][4] = {{0.f, 0.f, 0.f, 0.f}, {0.f, 0.f, 0.f, 0.f}};

    for (int it = 0; it < 64; it++) {
        const int buf = it & 1;
        *(uint4*)&ks[buf][srow * 136 + sco]     = ka;
        *(uint4*)&ks[buf][srow * 136 + sco + 8] = kb2;
        *(uint4*)&vth[buf][sdd * 40 + sk0]      = va;
        *(uint4*)&vth[buf][sdd * 40 + sk0 + 8]  = vb2;

        __syncthreads();

        {   // prefetch next tile (full compute phase of latency cover)
            const int ktn = (it < 63) ? (it + 1) * 32 : it * 32;
            const u16t* src = kb + (size_t)ktn * 128 + t * 16;
            ka  = *(const uint4*)(src);
            kb2 = *(const uint4*)(src + 8);
            const u16t* srch = vhg + (size_t)(ktn >> 5) * 4096 + t * 16;
            va  = *(const uint4*)(srch);
            vb2 = *(const uint4*)(srch + 8);
        }

        // col masks straight from global (16KB array, L1/L2-resident)
        const int colm0 = mask[mb + it * 32 + l15];
        const int colm1 = mask[mb + it * 32 + 16 + l15];

        f32x4 s4[2][2];
        #pragma unroll
        for (int i = 0; i < 2; i++)
            #pragma unroll
            for (int n = 0; n < 2; n++) s4[i][n] = (f32x4){0.f, 0.f, 0.f, 0.f};
        __builtin_amdgcn_s_setprio(1);
        #pragma unroll
        for (int kk = 0; kk < 4; kk++) {
            bf16x8 kf0 = *(const bf16x8*)&ks[buf][l15 * 136 + kk * 32 + quad * 8];
            bf16x8 kf1 = *(const bf16x8*)&ks[buf][(16 + l15) * 136 + kk * 32 + quad * 8];
            s4[0][0] = __builtin_amdgcn_mfma_f32_16x16x32_bf16(qf[0][kk], kf0, s4[0][0], 0, 0, 0);
            s4[0][1] = __builtin_amdgcn_mfma_f32_16x16x32_bf16(qf[0][kk], kf1, s4[0][1], 0, 0, 0);
            s4[1][0] = __builtin_amdgcn_mfma_f32_16x16x32_bf16(qf[1][kk], kf0, s4[1][0], 0, 0, 0);
            s4[1][1] = __builtin_amdgcn_mfma_f32_16x16x32_bf16(qf[1][kk], kf1, s4[1][1], 0, 0, 0);
        }
        __builtin_amdgcn_s_setprio(0);
        {   // col mask + exp2 -> packed bf16 P (row mask applied at epilogue)
            #pragma unroll
            for (int i = 0; i < 2; i++)
                #pragma unroll
                for (int r = 0; r < 4; r++) {
                    float w0 = colm0 ? 0.f : EXP2(s4[i][0][r]);
                    float w1 = colm1 ? 0.f : EXP2(s4[i][1][r]);
                    dsum[i][r] += w0 + w1;
                    u32t pkw;
                    asm("v_cvt_pk_bf16_f32 %0, %1, %2" : "=v"(pkw) : "v"(w0), "v"(w1));
                    *(u32t*)&wlb[rowoff[i] + r * 40 + 2 * l15] = pkw;
                }
        }
        bf16x8 pa[2];
        #pragma unroll
        for (int i = 0; i < 2; i++)
            pa[i] = *(const bf16x8*)&wlb[(16 * (2 * wid + i) + l15) * 40 + quad * 8];
        __builtin_amdgcn_s_setprio(1);
        #pragma unroll
        for (int dt = 0; dt < 8; dt++) {
            bf16x8 vh = *(const bf16x8*)&vth[buf][(16 * dt + l15) * 40 + quad * 8];
            acc[0][dt] = __builtin_amdgcn_mfma_f32_16x16x32_bf16(pa[0], vh, acc[0][dt], 0, 0, 0);
            acc[1][dt] = __builtin_amdgcn_mfma_f32_16x16x32_bf16(pa[1], vh, acc[1][dt], 0, 0, 0);
        }
        __builtin_amdgcn_s_setprio(0);
    }

    #pragma unroll
    for (int i = 0; i < 2; i++)
        #pragma unroll
        for (int r = 0; r < 4; r++) {
            float v = dsum[i][r];
            v += __shfl_xor(v, 1);
            v += __shfl_xor(v, 2);
            v += __shfl_xor(v, 4);
            v += __shfl_xor(v, 8);
            dsum[i][r] = v;
        }

    #pragma unroll
    for (int i = 0; i < 2; i++)
        #pragma unroll
        for (int r = 0; r < 4; r++) {
            int row = 16 * (2 * wid + i) + 4 * quad + r;
            float inv = (qmr[i][r] || !(dsum[i][r] > 0.f)) ? 0.f : 1.f / dsum[i][r];
            u16t* dst = O3b + (size_t)(z * SQ + q0 + row) * KOUT + h * 128;
            #pragma unroll
            for (int dt = 0; dt < 8; dt++)
                dst[16 * dt + l15] = f2bf(cubef(acc[i][dt][r] * inv));
        }
}

// ---------------- K4: partial[s] = O3b[:, chunk] @ W[chunk, :] — 4-buf ring, KSPLIT=8 ----------------
#define GQ_WAITBAR(N) do {                                                 \
    asm volatile("s_waitcnt vmcnt(" #N ")" ::: "memory");                  \
    __builtin_amdgcn_s_barrier();                                          \
    __builtin_amdgcn_sched_barrier(0);                                     \
} while (0)

#define GQ_STAGE(TI) do {                                                  \
    const int _k0 = (TI) * 32;                                             \
    const int _bb = ((TI) & 3) * 8192;                                     \
    load_lds16(aPtr + _k0,     &smem[_bb + wbase]);                        \
    load_lds16(aPtr + _k0 + 8, &smem[_bb + wbase + 1024]);                 \
    load_lds16(bPtr + _k0,     &smem[_bb + 4096 + wbase]);                 \
    load_lds16(bPtr + _k0 + 8, &smem[_bb + 4096 + wbase + 1024]);          \
} while (0)

#define GQ_COMPUTE(TI) do {                                                \
    const int _bb = ((TI) & 3) * 8192;                                     \
    bf16x8 ah[4], bh[4];                                                   \
    _Pragma("unroll")                                                      \
    for (int mt = 0; mt < 4; mt++)                                         \
        ah[mt] = *(const bf16x8*)&smem[_bb + quad * 1024 + (wm + mt * 16 + l15) * 8]; \
    _Pragma("unroll")                                                      \
    for (int nt = 0; nt < 4; nt++)                                         \
        bh[nt] = *(const bf16x8*)&smem[_bb + 4096 + quad * 1024 + (wn + nt * 16 + l15) * 8]; \
    _Pragma("unroll")                                                      \
    for (int mt = 0; mt < 4; mt++)                                         \
        _Pragma("unroll")                                                  \
        for (int nt = 0; nt < 4; nt++)                                     \
            acc[mt][nt] = __builtin_amdgcn_mfma_f32_16x16x32_bf16(ah[mt], bh[nt], acc[mt][nt], 0, 0, 0); \
} while (0)

__global__ __launch_bounds__(256, 2) void final_gemm4(const u16t* __restrict__ Ab,
                                                      const u16t* __restrict__ Bh,
                                                      float* __restrict__ part) {
    __shared__ __align__(16) u16t smem[32768];

    const int t = threadIdx.x;
    const int lane = t & 63, wid = t >> 6;
    const int quad = lane >> 4, l15 = lane & 15;
    const int wm = (wid & 1) * 64;
    const int wn = (wid >> 1) * 64;
    const int rowBase = blockIdx.x * 128;
    const int kBase   = blockIdx.y * (KOUT / KSPLIT);   // 256
    const int sm = t & 127;
    const int skh = t >> 7;

    f32x4 acc[4][4];
    #pragma unroll
    for (int i = 0; i < 4; i++)
        #pragma unroll
        for (int j = 0; j < 4; j++) acc[i][j] = (f32x4){0.f, 0.f, 0.f, 0.f};

    const u16t* aPtr = Ab + (size_t)(rowBase + sm) * KOUT + kBase + skh * 16;
    const u16t* bPtr = Bh + (size_t)sm * KOUT + kBase + skh * 16;
    const int wbase = (wid >> 1) * 2048 + (wid & 1) * 512;

    GQ_STAGE(0);
    GQ_STAGE(1);
    for (int i = 0; i < 6; i++) {
        GQ_STAGE(i + 2);
        GQ_WAITBAR(8);
        GQ_COMPUTE(i);
    }
    GQ_WAITBAR(4);
    GQ_COMPUTE(6);
    GQ_WAITBAR(0);
    GQ_COMPUTE(7);

    float* pbase = part + (size_t)blockIdx.y * ((size_t)MROWS * 128);
    #pragma unroll
    for (int mt = 0; mt < 4; mt++)
        #pragma unroll
        for (int nt = 0; nt < 4; nt++) {
            int col = wn + nt * 16 + l15;
            #pragma unroll
            for (int r = 0; r < 4; r++) {
                int row = rowBase + wm + mt * 16 + quad * 4 + r;
                pbase[(size_t)row * 128 + col] = acc[mt][nt][r];
            }
        }
}

// ---------------- K5: out = cube(sum partials + bias) ----------------
__global__ __launch_bounds__(256) void reduce_bias_cube(const float* __restrict__ part,
                                                        const float* __restrict__ bias,
                                                        float* __restrict__ out) {
    const int idx = (blockIdx.x * 256 + threadIdx.x) * 4;
    float4 s = {0.f, 0.f, 0.f, 0.f};
    #pragma unroll
    for (int p = 0; p < KSPLIT; p++) {
        float4 v = *(const float4*)&part[(size_t)p * ((size_t)MROWS * 128) + idx];
        s.x += v.x; s.y += v.y; s.z += v.z; s.w += v.w;
    }
    float4 b = *(const float4*)&bias[idx & 127];
    float4 r;
    r.x = cubef(s.x + b.x);
    r.y = cubef(s.y + b.y);
    r.z = cubef(s.z + b.z);
    r.w = cubef(s.w + b.w);
    *(float4*)&out[idx] = r;
}

extern "C" void kernel_launch(void* const* d_in, const int* in_sizes, int n_in,
                              void* d_out, int out_size, void* d_ws, size_t ws_size,
                              hipStream_t stream) {
    const float* x        = (const float*)d_in[0];
    const int*   mask     = (const int*)d_in[1];
    const float* proj_in  = (const float*)d_in[2];
    const float* v_bias   = (const float*)d_in[3];
    const float* proj_out = (const float*)d_in[4];
    const float* po_bias  = (const float*)d_in[5];
    float* out = (float*)d_out;

    u16t* QB  = (u16t*)d_ws;                      // 16 MB
    u16t* KB  = QB + (size_t)8388608;             // 16 MB
    u16t* VTh = KB + (size_t)8388608;             // 16 MB
    u16t* xb  = VTh + (size_t)8388608;            // 8 MB
    u16t* O3b = xb + (size_t)4194304;             // 16 MB
    u16t* pTh = O3b;                              // aliases O3b head (dead before attn)
    float* ropetab = (float*)(O3b + (size_t)6291456);   // aliases O3b tail
    u16t* WTh = QB;                               // 0.5 MB (dead after attn)
    float* partials = (float*)(WTh + (size_t)128 * KOUT);  // [8,4096,128] f32 16.8 MB

    prep_all<<<2048 + 512 + 1536, 256, 0, stream>>>(x, xb, ropetab, proj_in, pTh);
    gemm_qkv11<<<dim3(48, 32), 256, 0, stream>>>(xb, pTh, v_bias, ropetab, QB, KB, VTh);
    attn_kernel13<<<BZ * HH * (SQ / 128), 256, 0, stream>>>(QB, KB, VTh, mask, O3b);
    transpose_w2<<<dim3(2, KOUT / 64), 256, 0, stream>>>(proj_out, WTh);
    final_gemm4<<<dim3(MROWS / 128, KSPLIT), 256, 0, stream>>>(O3b, WTh, partials);
    reduce_bias_cube<<<(MROWS * 128) / (256 * 4), 256, 0, stream>>>(partials, po_bias, out);
}